// Round 7
// baseline (138.165 us; speedup 1.0000x reference)
//
#include <hip/hip_runtime.h>
#include <hip/hip_bf16.h>

typedef unsigned short u16;
typedef unsigned int u32;
typedef __attribute__((ext_vector_type(8))) short bf16x8;   // 8 bf16 (4 VGPRs)
typedef __attribute__((ext_vector_type(8))) u16 u16x8;
typedef __attribute__((ext_vector_type(4))) u16 u16x4;
typedef __attribute__((ext_vector_type(4))) u32 u32x4;
typedef __attribute__((ext_vector_type(4))) float f32x4;
typedef __attribute__((ext_vector_type(4))) _Float16 f16x4;
typedef __attribute__((ext_vector_type(16))) float f32x16;

typedef const __attribute__((address_space(1))) void* gas1_t;
typedef __attribute__((address_space(3))) void* las3_t;

#define MFMA16(a,b,c) __builtin_amdgcn_mfma_f32_16x16x32_bf16((a),(b),(c),0,0,0)
#define MFMA32(a,b,c) __builtin_amdgcn_mfma_f32_32x32x16_bf16((a),(b),(c),0,0,0)

static constexpr int BB = 4, SS = 1024, DD = 1024, HH = 16;

static __device__ __forceinline__ u16 f2b(float x) {
  union { __hip_bfloat16 h; u16 u; } cv;
  cv.h = __float2bfloat16(x);
  return cv.u;
}
static __device__ __forceinline__ u32 pk2(float a, float b) {
  return (u32)f2b(a) | ((u32)f2b(b) << 16);
}

// ---------------- fused fp32 -> bf16 conversion (q,k,v + 4 weights) ----------------
__global__ __launch_bounds__(256) void cvt_all(
    const float* __restrict__ q, const float* __restrict__ k, const float* __restrict__ v,
    const float* __restrict__ wq_, const float* __restrict__ wk_, const float* __restrict__ wv_,
    const float* __restrict__ wp_,
    u16* __restrict__ qb, u16* __restrict__ kb, u16* __restrict__ vb,
    u16* __restrict__ wqb, u16* __restrict__ wkb, u16* __restrict__ wvb, u16* __restrict__ wpb) {
  int bid = blockIdx.x;
  const float* s; u16* d; int off;
  if      (bid < 4096)  { s = q;   d = qb;  off = bid; }
  else if (bid < 8192)  { s = k;   d = kb;  off = bid - 4096; }
  else if (bid < 12288) { s = v;   d = vb;  off = bid - 8192; }
  else if (bid < 13312) { s = wq_; d = wqb; off = bid - 12288; }
  else if (bid < 14336) { s = wk_; d = wkb; off = bid - 13312; }
  else if (bid < 15360) { s = wv_; d = wvb; off = bid - 14336; }
  else                  { s = wp_; d = wpb; off = bid - 15360; }
  int i = (off * 256 + threadIdx.x) * 4;
  float4 val = *(const float4*)(s + i);
  u16x4 r = { f2b(val.x), f2b(val.y), f2b(val.z), f2b(val.w) };
  *(u16x4*)(d + i) = r;
}

// ---------------- bias fp32 -> fp16 (launched after transpose_v; dst overlays dead kb) ----
__global__ __launch_bounds__(256) void cvt_bias(const float* __restrict__ src,
                                                _Float16* __restrict__ dst) {
  int i = (blockIdx.x * 256 + threadIdx.x) * 4;
  float4 v = *(const float4*)(src + i);
  f16x4 r = { (_Float16)v.x, (_Float16)v.y, (_Float16)v.z, (_Float16)v.w };
  *(f16x4*)(dst + i) = r;
}

// ---------------- GEMM: C[M,N] = A[M,K] * W[N,K]^T  (m97-style 128x128 tile) ----------------
template<typename OT>
__global__ __launch_bounds__(256) void gemm_bt(
    const u16* __restrict__ Abase, const u16* __restrict__ Wbase, OT* __restrict__ Cbase,
    int N, int K, size_t sA, size_t sW, size_t sC) {
  const u16* A = Abase + (size_t)blockIdx.z * sA;
  const u16* W = Wbase + (size_t)blockIdx.z * sW;
  OT* C = Cbase + (size_t)blockIdx.z * sC;

  __shared__ __align__(16) u16 As[128 * 32];
  __shared__ __align__(16) u16 Bs[128 * 32];

  const int tid = threadIdx.x;
  const int lane = tid & 63;
  const int wid = tid >> 6;
  const int g = lane >> 4;
  const int li = lane & 15;
  const int brow = blockIdx.y * 128;
  const int bcol = blockIdx.x * 128;
  const int wr = (wid >> 1) * 64;
  const int wc = (wid & 1) * 64;

  const int srow = tid >> 2;
  const int scol = (tid & 3) * 8;

  f32x4 acc[4][4] = {};

  for (int k0 = 0; k0 < K; k0 += 32) {
#pragma unroll
    for (int c = 0; c < 2; ++c) {
      const u16* ga = A + (size_t)(brow + srow + c * 64) * K + k0 + scol;
      const u16* gw = W + (size_t)(bcol + srow + c * 64) * K + k0 + scol;
      __builtin_amdgcn_global_load_lds((gas1_t)(const void*)ga,
                                       (las3_t)(void*)(As + wid * 512 + c * 2048), 16, 0, 0);
      __builtin_amdgcn_global_load_lds((gas1_t)(const void*)gw,
                                       (las3_t)(void*)(Bs + wid * 512 + c * 2048), 16, 0, 0);
    }
    __syncthreads();

    bf16x8 a[4], b[4];
#pragma unroll
    for (int m = 0; m < 4; ++m)
      a[m] = *(const bf16x8*)&As[(wr + m * 16 + li) * 32 + g * 8];
#pragma unroll
    for (int n = 0; n < 4; ++n)
      b[n] = *(const bf16x8*)&Bs[(wc + n * 16 + li) * 32 + g * 8];
#pragma unroll
    for (int m = 0; m < 4; ++m)
#pragma unroll
      for (int n = 0; n < 4; ++n)
        acc[m][n] = MFMA16(a[m], b[n], acc[m][n]);
    __syncthreads();
  }

#pragma unroll
  for (int m = 0; m < 4; ++m)
#pragma unroll
    for (int n = 0; n < 4; ++n)
#pragma unroll
      for (int j = 0; j < 4; ++j) {
        int r = brow + wr + m * 16 + g * 4 + j;
        int c = bcol + wc + n * 16 + li;
        if constexpr (sizeof(OT) == 2) C[(size_t)r * N + c] = (OT)f2b(acc[m][n][j]);
        else                           C[(size_t)r * N + c] = acc[m][n][j];
      }
}

// ---------------- V transpose: V[b*S+s][h*64+dv] -> Vt[((b*H+h)*64+dv)*S + s] ----------------
__global__ __launch_bounds__(256) void transpose_v(const u16* __restrict__ V, u16* __restrict__ Vt) {
  __shared__ __align__(16) u16 t[64][72];
  const int s0 = blockIdx.x * 64, h = blockIdx.y, b = blockIdx.z;
  const int tid = threadIdx.x;
#pragma unroll
  for (int it = 0; it < 2; ++it) {
    int slot = tid + it * 256;
    int r = slot >> 3, seg = slot & 7;
    *(u16x8*)&t[r][seg * 8] = *(const u16x8*)&V[(size_t)(b * SS + s0 + r) * DD + h * 64 + seg * 8];
  }
  __syncthreads();
#pragma unroll
  for (int it = 0; it < 2; ++it) {
    int slot = tid + it * 256;
    int dv = slot >> 3, seg = slot & 7;
    u16x8 v;
#pragma unroll
    for (int i = 0; i < 8; ++i) v[i] = t[seg * 8 + i][dv];
    *(u16x8*)&Vt[(size_t)((b * HH + h) * 64 + dv) * SS + s0 + seg * 8] = v;
  }
}

// ---------------- fused flash attention: ONE barrier per tile, fp16 bias dbuf ----------------
// grid: (S/128, H, B) XCD-remapped; block 256 = 4 waves, each wave owns 32 q-rows (q = lane&31).
// All three tile inputs (K, V, bias16) are double-buffered; the only __syncthreads is at
// tile end, so the vmcnt drain there happens after a full tile of compute cover.
__global__ __launch_bounds__(256) void attn_kernel(
    const u16* __restrict__ Q, const u16* __restrict__ K, const u16* __restrict__ Vt,
    const _Float16* __restrict__ bias16, u16* __restrict__ O) {
  __shared__ __align__(16) u16 kbuf[2][64 * 64];   // [k][d], XOR-swizzled      (16 KB)
  __shared__ __align__(16) u16 vbuf[2][64 * 64];   // [dv][k], XOR-swizzled     (16 KB)
  __shared__ __align__(16) u16 bbuf[2][8192];      // fp16 bias [qq][granule^row] (2x16 KB)

  const int tid = threadIdx.x;
  const int lane = tid & 63;
  const int wq = tid >> 6;
  const int hi = lane >> 5;
  const int ln = lane & 31;
  const u32 swz = (u32)(ln & 7) << 4;

  // bijective XCD-chunked remap: 512 blocks = 8 XCDs x 64
  const int flat = blockIdx.x + (blockIdx.y << 3) + (blockIdx.z << 7);
  const int L = ((flat & 7) << 6) | (flat >> 3);
  const int qt = L & 7, h = (L >> 3) & 15, b = L >> 7;
  const int q0 = qt * 128;
  const int qrow = q0 + wq * 32 + ln;       // this lane's softmax row

  // Q B-fragments: lane holds Q[qrow][d = dstep*16 + hi*8 + e]
  bf16x8 qf[4];
  {
    const u16* qp = Q + (size_t)(b * SS + qrow) * DD + h * 64 + hi * 8;
#pragma unroll
    for (int d = 0; d < 4; ++d) qf[d] = *(const bf16x8*)(qp + d * 16);
  }

  // K/V staging map: thread -> (row sr, 32B chunk)
  const int sr = tid >> 2;
  const int scb = (tid & 3) * 32;
  const u16* kg = K + (size_t)(b * SS + sr) * DD + h * 64 + scb / 2;
  const u16* vg = Vt + (size_t)((b * HH + h) * 64 + sr) * SS + scb / 2;
  const u32 wa0 = (u32)sr * 128 + (((u32)scb) ^ ((u32)(sr & 7) << 4));
  const u32 wa1 = (u32)sr * 128 + (((u32)scb + 16) ^ ((u32)(sr & 7) << 4));

  // bias16 staging: per issue i (0..3) wave wq covers rows i*32 + wq*8 + (lane>>3),
  // physical granule lane&7 holds logical granule (lane&7)^(row&7); LDS dest is linear.
  const int r_l = lane >> 3;
  const int gl = (lane & 7) ^ r_l;
  const _Float16* bsrc = bias16 + (size_t)(b * SS + q0 + wq * 8 + r_l) * SS + gl * 8;

  // bias read addresses (fixed): element block (kb,rq): 8B at
  //   qq*128 + ((kb*4+rq) ^ (qq&7))*16 + hi*8
  const int qq = wq * 32 + ln;
  int baddr[2][4];
#pragma unroll
  for (int kb = 0; kb < 2; ++kb)
#pragma unroll
    for (int rq = 0; rq < 4; ++rq)
      baddr[kb][rq] = qq * 128 + (((kb * 4 + rq) ^ (ln & 7)) << 4) + hi * 8;

  // ---- prologue: stage tile 0 (bias via gload_lds, K/V via regs) ----
  {
    char* bd = (char*)bbuf[0] + wq * 1024;
#pragma unroll
    for (int i = 0; i < 4; ++i)
      __builtin_amdgcn_global_load_lds((gas1_t)(const void*)(bsrc + (size_t)i * 32 * SS),
                                       (las3_t)(void*)(bd + i * 4096), 16, 0, 0);
  }
  u16x8 kr0, kr1, vr0, vr1;
  kr0 = *(const u16x8*)(kg + 0);
  kr1 = *(const u16x8*)(kg + 8);
  vr0 = *(const u16x8*)(vg + 0);
  vr1 = *(const u16x8*)(vg + 8);
  *(u16x8*)((char*)kbuf[0] + wa0) = kr0;
  *(u16x8*)((char*)kbuf[0] + wa1) = kr1;
  *(u16x8*)((char*)vbuf[0] + wa0) = vr0;
  *(u16x8*)((char*)vbuf[0] + wa1) = vr1;
  __syncthreads();

  f32x16 o0 = {}, o1 = {};
  float m = -1e30f, lsum = 0.f;
  int cur = 0;

  for (int kt = 0; kt < 16; ++kt) {
    // 1. stage next tile: bias[kt+1] -> bbuf[cur^1] (async LDS), K/V[kt+1] -> regs
    if (kt < 15) {
      char* bd = (char*)bbuf[cur ^ 1] + wq * 1024;
      const _Float16* bs = bsrc + (kt + 1) * 64;
#pragma unroll
      for (int i = 0; i < 4; ++i)
        __builtin_amdgcn_global_load_lds((gas1_t)(const void*)(bs + (size_t)i * 32 * SS),
                                         (las3_t)(void*)(bd + i * 4096), 16, 0, 0);
      const size_t k1 = (size_t)(kt + 1) * 64;
      kr0 = *(const u16x8*)(kg + k1 * DD + 0);
      kr1 = *(const u16x8*)(kg + k1 * DD + 8);
      vr0 = *(const u16x8*)(vg + k1 + 0);
      vr1 = *(const u16x8*)(vg + k1 + 8);
    }

    // 2. swapped QK^T: s = mfma(K, Q) -> C: col = q = ln, row(k) = (r&3)+8*(r>>2)+4*hi (+32*kb)
    const char* kb_base = (const char*)kbuf[cur];
    f32x16 s[2];
#pragma unroll
    for (int kb = 0; kb < 2; ++kb) {
      f32x16 acc = {};
#pragma unroll
      for (int d = 0; d < 4; ++d) {
        bf16x8 kf = *(const bf16x8*)(kb_base + (kb * 32 + ln) * 128 + (((u32)(d * 32 + hi * 16)) ^ swz));
        acc = MFMA32(kf, qf[d], acc);
      }
      s[kb] = acc;
    }

    // 3. scale (D^-0.5 = 1/32) + bias (fp16 LDS tile staged LAST tile -> already visible)
    const char* bbr = (const char*)bbuf[cur];
#pragma unroll
    for (int kb = 0; kb < 2; ++kb)
#pragma unroll
      for (int rq = 0; rq < 4; ++rq) {
        f16x4 bv = *(const f16x4*)(bbr + baddr[kb][rq]);
#pragma unroll
        for (int c = 0; c < 4; ++c)
          s[kb][rq * 4 + c] = fmaf(s[kb][rq * 4 + c], 0.03125f, (float)bv[c]);
      }

    // 4. in-register row softmax (row is lane-local; only cross-hi shuffle needed)
    float mt = -1e30f;
#pragma unroll
    for (int r = 0; r < 16; ++r) { mt = fmaxf(mt, s[0][r]); mt = fmaxf(mt, s[1][r]); }
    mt = fmaxf(mt, __shfl_xor(mt, 32));

    bool resc = false;
    float fsc = 1.f;
    if (kt == 0) {
      m = mt;
    } else if (__any(mt > m + 8.f)) {   // T13 defer-max
      float mn = fmaxf(m, mt);
      fsc = __expf(m - mn);
      m = mn;
      resc = true;
    }

    float rs = 0.f;
    u32 wv[2][8];
#pragma unroll
    for (int kb = 0; kb < 2; ++kb)
#pragma unroll
      for (int t = 0; t < 8; ++t) {
        float p0 = __expf(s[kb][2 * t] - m);
        float p1 = __expf(s[kb][2 * t + 1] - m);
        rs += p0 + p1;
        wv[kb][t] = pk2(p0, p1);
      }
    rs += __shfl_xor(rs, 32);
    lsum = lsum * fsc + rs;

    if (resc) {  // rescale O at q' = crow(j,hi), factor fetched via lane broadcast
#pragma unroll
      for (int j = 0; j < 16; ++j) {
        float fv = __shfl(fsc, (j & 3) + 8 * (j >> 2) + 4 * hi);
        o0[j] *= fv; o1[j] *= fv;
      }
    }

    // 5. PV: rebuild P A-fragments in-register (cross-hi shfl), then mfma(P, V)
    const char* vb_base = (const char*)vbuf[cur];
#pragma unroll
    for (int ks = 0; ks < 4; ++ks) {
      const int kb = ks >> 1, i0 = (ks & 1) * 4;
      u32 sA = hi ? wv[kb][i0 + 0] : wv[kb][i0 + 2];
      u32 sB = hi ? wv[kb][i0 + 1] : wv[kb][i0 + 3];
      u32 rA = (u32)__shfl_xor((int)sA, 32);
      u32 rB = (u32)__shfl_xor((int)sB, 32);
      u32 e0 = hi ? rA : wv[kb][i0 + 0];
      u32 e1 = hi ? rB : wv[kb][i0 + 1];
      u32 e2 = hi ? wv[kb][i0 + 2] : rA;
      u32 e3 = hi ? wv[kb][i0 + 3] : rB;
      union { u32x4 u; bf16x8 v; } pc;
      pc.u = (u32x4){e0, e1, e2, e3};
      bf16x8 pa = pc.v;
#pragma unroll
      for (int nv = 0; nv < 2; ++nv) {
        bf16x8 vf = *(const bf16x8*)(vb_base + (nv * 32 + ln) * 128 + (((u32)(ks * 32 + hi * 16)) ^ swz));
        if (nv == 0) o0 = MFMA32(pa, vf, o0);
        else         o1 = MFMA32(pa, vf, o1);
      }
    }

    // 6. write next K/V tile into the other buffer; 7. single end-of-tile barrier
    if (kt < 15) {
      char* kd = (char*)kbuf[cur ^ 1];
      char* vd = (char*)vbuf[cur ^ 1];
      *(u16x8*)(kd + wa0) = kr0;
      *(u16x8*)(kd + wa1) = kr1;
      *(u16x8*)(vd + wa0) = vr0;
      *(u16x8*)(vd + wa1) = vr1;
      __syncthreads();
      cur ^= 1;
    }
  }

  // epilogue: normalize (1/l broadcast via shfl) + write O (bf16)
  float inv = 1.0f / lsum;
#pragma unroll
  for (int j = 0; j < 16; ++j) {
    float iv = __shfl(inv, (j & 3) + 8 * (j >> 2) + 4 * hi);
    int q = q0 + wq * 32 + (j & 3) + 8 * (j >> 2) + 4 * hi;
    u16* op = O + (size_t)(b * SS + q) * DD + h * 64 + ln;
    op[0]  = f2b(o0[j] * iv);
    op[32] = f2b(o1[j] * iv);
  }
}

// ---------------- host launch ----------------
extern "C" void kernel_launch(void* const* d_in, const int* in_sizes, int n_in,
                              void* d_out, int out_size, void* d_ws, size_t ws_size,
                              hipStream_t stream) {
  const float* queries = (const float*)d_in[0];
  const float* keys    = (const float*)d_in[1];
  const float* values  = (const float*)d_in[2];
  const float* bias    = (const float*)d_in[3];
  const float* Wq      = (const float*)d_in[4];
  const float* Wk      = (const float*)d_in[5];
  const float* Wv      = (const float*)d_in[6];
  const float* Wp      = (const float*)d_in[7];
  float* out = (float*)d_out;

  char* ws = (char*)d_ws;
  const size_t MB = 1024 * 1024;
  u16* qb  = (u16*)(ws + 0 * MB);
  u16* kb  = (u16*)(ws + 8 * MB);
  u16* vb  = (u16*)(ws + 16 * MB);
  u16* wqb = (u16*)(ws + 24 * MB);
  u16* wkb = (u16*)(ws + 26 * MB);
  u16* wvb = (u16*)(ws + 28 * MB);
  u16* wpb = (u16*)(ws + 30 * MB);
  u16* Qb  = (u16*)(ws + 32 * MB);
  u16* Kb  = (u16*)(ws + 40 * MB);
  u16* Vb  = (u16*)(ws + 48 * MB);
  u16* Vtb = (u16*)(ws + 56 * MB);
  // bias16 (8.39 MB) overlays kb + head of vb — both dead after transpose_v
  _Float16* bias16 = (_Float16*)(ws + 8 * MB);
  u16* Ob  = (u16*)(ws + 0 * MB);  // attn output over qb (dead after projections)

  const int nAct = BB * SS * DD;  // 4M
  const int nW = DD * DD;         // 1M

  cvt_all<<<dim3(16384), dim3(256), 0, stream>>>(
      queries, keys, values, Wq, Wk, Wv, Wp,
      qb, kb, vb, wqb, wkb, wvb, wpb);

  gemm_bt<u16><<<dim3(8, 32, 3), dim3(256), 0, stream>>>(
      qb, wqb, Qb, DD, DD, (size_t)nAct, (size_t)nW, (size_t)nAct);

  transpose_v<<<dim3(16, 16, 4), dim3(256), 0, stream>>>(Vb, Vtb);

  // bias fp32 -> fp16 (kb/vb regions are dead from here on)
  cvt_bias<<<dim3(4096), dim3(256), 0, stream>>>(bias, bias16);

  attn_kernel<<<dim3(8, 16, 4), dim3(256), 0, stream>>>(Qb, Kb, Vtb, bias16, Ob);

  gemm_bt<float><<<dim3(8, 32, 1), dim3(256), 0, stream>>>(
      Ob, wpb, out, DD, DD, 0, 0, 0);
}

// Round 8
// 118.059 us; speedup vs baseline: 1.1703x; 1.1703x over previous
//
#include <hip/hip_runtime.h>
#include <hip/hip_bf16.h>

typedef unsigned short u16;
typedef unsigned int u32;
typedef __attribute__((ext_vector_type(8))) short bf16x8;   // 8 bf16 (4 VGPRs)
typedef __attribute__((ext_vector_type(8))) u16 u16x8;
typedef __attribute__((ext_vector_type(4))) u16 u16x4;
typedef __attribute__((ext_vector_type(4))) u32 u32x4;
typedef __attribute__((ext_vector_type(4))) float f32x4;
typedef __attribute__((ext_vector_type(4))) _Float16 f16x4;
typedef __attribute__((ext_vector_type(16))) float f32x16;

typedef const __attribute__((address_space(1))) void* gas1_t;
typedef __attribute__((address_space(3))) void* las3_t;

#define MFMA16(a,b,c) __builtin_amdgcn_mfma_f32_16x16x32_bf16((a),(b),(c),0,0,0)
#define MFMA32(a,b,c) __builtin_amdgcn_mfma_f32_32x32x16_bf16((a),(b),(c),0,0,0)

static constexpr int BB = 4, SS = 1024, DD = 1024, HH = 16;

static __device__ __forceinline__ u16 f2b(float x) {
  union { __hip_bfloat16 h; u16 u; } cv;
  cv.h = __float2bfloat16(x);
  return cv.u;
}
static __device__ __forceinline__ u32 pk2(float a, float b) {
  return (u32)f2b(a) | ((u32)f2b(b) << 16);
}

// ---------------- fused fp32 -> bf16 conversion (q,k,v + 4 weights) ----------------
__global__ __launch_bounds__(256) void cvt_all(
    const float* __restrict__ q, const float* __restrict__ k, const float* __restrict__ v,
    const float* __restrict__ wq_, const float* __restrict__ wk_, const float* __restrict__ wv_,
    const float* __restrict__ wp_,
    u16* __restrict__ qb, u16* __restrict__ kb, u16* __restrict__ vb,
    u16* __restrict__ wqb, u16* __restrict__ wkb, u16* __restrict__ wvb, u16* __restrict__ wpb) {
  int bid = blockIdx.x;
  const float* s; u16* d; int off;
  if      (bid < 4096)  { s = q;   d = qb;  off = bid; }
  else if (bid < 8192)  { s = k;   d = kb;  off = bid - 4096; }
  else if (bid < 12288) { s = v;   d = vb;  off = bid - 8192; }
  else if (bid < 13312) { s = wq_; d = wqb; off = bid - 12288; }
  else if (bid < 14336) { s = wk_; d = wkb; off = bid - 13312; }
  else if (bid < 15360) { s = wv_; d = wvb; off = bid - 14336; }
  else                  { s = wp_; d = wpb; off = bid - 15360; }
  int i = (off * 256 + threadIdx.x) * 4;
  float4 val = *(const float4*)(s + i);
  u16x4 r = { f2b(val.x), f2b(val.y), f2b(val.z), f2b(val.w) };
  *(u16x4*)(d + i) = r;
}

// ---------------- bias fp32 -> fp16 (dst overlays dead kb region) ----------------
__global__ __launch_bounds__(256) void cvt_bias(const float* __restrict__ src,
                                                _Float16* __restrict__ dst) {
  int i = (blockIdx.x * 256 + threadIdx.x) * 4;
  float4 v = *(const float4*)(src + i);
  f16x4 r = { (_Float16)v.x, (_Float16)v.y, (_Float16)v.z, (_Float16)v.w };
  *(f16x4*)(dst + i) = r;
}

// ---------------- GEMM: C[M,N] = A[M,K] * W[N,K]^T ----------------
// 128x128 tile, BK=64, T2 source-pre-swizzled LDS (bank-conflict-free ds_read_b128),
// XCD-chunked block swizzle. vtrans: z==2 writes V^T directly (Vt layout) to Tout.
template<typename OT, bool VTRANS>
__global__ __launch_bounds__(256) void gemm_bt(
    const u16* __restrict__ Abase, const u16* __restrict__ Wbase, OT* __restrict__ Cbase,
    u16* __restrict__ Tout, int N, int K, size_t sA, size_t sW, size_t sC) {
  const u16* A = Abase + (size_t)blockIdx.z * sA;
  const u16* W = Wbase + (size_t)blockIdx.z * sW;
  OT* C = Cbase + (size_t)blockIdx.z * sC;

  __shared__ __align__(16) u16 As[128 * 64];
  __shared__ __align__(16) u16 Bs[128 * 64];

  const int tid = threadIdx.x;
  const int lane = tid & 63;
  const int wid = tid >> 6;
  const int g = lane >> 4;
  const int li = lane & 15;

  // XCD-chunked swizzle within each z: XCD c gets 4 consecutive row-panels x all col-tiles
  const int hw = blockIdx.x + (blockIdx.y << 3);          // 0..255
  const int L = ((hw & 7) << 5) + (hw >> 3);
  const int brow = (L >> 3) * 128;
  const int bcol = (L & 7) * 128;

  const int wr = (wid >> 1) * 64;
  const int wc = (wid & 1) * 64;

  // staging: issue i covers rows i*32 + wid*8 + (lane>>3); source col-chunk pre-swizzled
  const int srow = wid * 8 + (lane >> 3);
  const int schunk = (lane & 7) ^ (lane >> 3);            // logical chunk loaded by this lane
  const u16* ga0 = A + (size_t)(brow + srow) * K + schunk * 8;
  const u16* gw0 = W + (size_t)(bcol + srow) * K + schunk * 8;

  f32x4 acc[4][4] = {};

  for (int k0 = 0; k0 < K; k0 += 64) {
#pragma unroll
    for (int i = 0; i < 4; ++i) {
      __builtin_amdgcn_global_load_lds((gas1_t)(const void*)(ga0 + (size_t)(i * 32) * K + k0),
                                       (las3_t)(void*)(As + (i * 32 + wid * 8) * 64), 16, 0, 0);
      __builtin_amdgcn_global_load_lds((gas1_t)(const void*)(gw0 + (size_t)(i * 32) * K + k0),
                                       (las3_t)(void*)(Bs + (i * 32 + wid * 8) * 64), 16, 0, 0);
    }
    __syncthreads();

#pragma unroll
    for (int kk = 0; kk < 2; ++kk) {
      bf16x8 a[4], b[4];
#pragma unroll
      for (int m = 0; m < 4; ++m) {
        int row = wr + m * 16 + li;
        a[m] = *(const bf16x8*)&As[row * 64 + (((kk * 4 + g) ^ (li & 7)) << 3)];
      }
#pragma unroll
      for (int n = 0; n < 4; ++n) {
        int row = wc + n * 16 + li;
        b[n] = *(const bf16x8*)&Bs[row * 64 + (((kk * 4 + g) ^ (li & 7)) << 3)];
      }
#pragma unroll
      for (int m = 0; m < 4; ++m)
#pragma unroll
        for (int n = 0; n < 4; ++n)
          acc[m][n] = MFMA16(a[m], b[n], acc[m][n]);
    }
    __syncthreads();
  }

  if (VTRANS && blockIdx.z == 2) {
    // write V^T directly: Vt[((b*H + h)*64 + dv)*S + s], 4 consecutive s per store
#pragma unroll
    for (int m = 0; m < 4; ++m) {
#pragma unroll
      for (int n = 0; n < 4; ++n) {
        int c = bcol + wc + n * 16 + li;
        int h_ = c >> 6, dv = c & 63;
        int r0 = brow + wr + m * 16 + g * 4;
        int b_ = r0 >> 10, s0 = r0 & 1023;
        u16x4 val = { f2b(acc[m][n][0]), f2b(acc[m][n][1]),
                      f2b(acc[m][n][2]), f2b(acc[m][n][3]) };
        *(u16x4*)&Tout[(size_t)((b_ * HH + h_) * 64 + dv) * SS + s0] = val;
      }
    }
  } else {
#pragma unroll
    for (int m = 0; m < 4; ++m)
#pragma unroll
      for (int n = 0; n < 4; ++n)
#pragma unroll
        for (int j = 0; j < 4; ++j) {
          int r = brow + wr + m * 16 + g * 4 + j;
          int c = bcol + wc + n * 16 + li;
          if constexpr (sizeof(OT) == 2) C[(size_t)r * N + c] = (OT)f2b(acc[m][n][j]);
          else                           C[(size_t)r * N + c] = acc[m][n][j];
        }
  }
}

// ---------------- fused flash attention: ONE barrier per tile, fp16 bias dbuf ----------------
// grid: (S/128, H, B) XCD-remapped; block 256 = 4 waves, each wave owns 32 q-rows (q = lane&31).
__global__ __launch_bounds__(256) void attn_kernel(
    const u16* __restrict__ Q, const u16* __restrict__ K, const u16* __restrict__ Vt,
    const _Float16* __restrict__ bias16, u16* __restrict__ O) {
  __shared__ __align__(16) u16 kbuf[2][64 * 64];   // [k][d], XOR-swizzled      (16 KB)
  __shared__ __align__(16) u16 vbuf[2][64 * 64];   // [dv][k], XOR-swizzled     (16 KB)
  __shared__ __align__(16) u16 bbuf[2][8192];      // fp16 bias [qq][granule^row] (2x16 KB)

  const int tid = threadIdx.x;
  const int lane = tid & 63;
  const int wq = tid >> 6;
  const int hi = lane >> 5;
  const int ln = lane & 31;
  const u32 swz = (u32)(ln & 7) << 4;

  // bijective XCD-chunked remap: 512 blocks = 8 XCDs x 64
  const int flat = blockIdx.x + (blockIdx.y << 3) + (blockIdx.z << 7);
  const int L = ((flat & 7) << 6) | (flat >> 3);
  const int qt = L & 7, h = (L >> 3) & 15, b = L >> 7;
  const int q0 = qt * 128;
  const int qrow = q0 + wq * 32 + ln;       // this lane's softmax row

  // Q B-fragments: lane holds Q[qrow][d = dstep*16 + hi*8 + e]
  bf16x8 qf[4];
  {
    const u16* qp = Q + (size_t)(b * SS + qrow) * DD + h * 64 + hi * 8;
#pragma unroll
    for (int d = 0; d < 4; ++d) qf[d] = *(const bf16x8*)(qp + d * 16);
  }

  // K/V staging map: thread -> (row sr, 32B chunk)
  const int sr = tid >> 2;
  const int scb = (tid & 3) * 32;
  const u16* kg = K + (size_t)(b * SS + sr) * DD + h * 64 + scb / 2;
  const u16* vg = Vt + (size_t)((b * HH + h) * 64 + sr) * SS + scb / 2;
  const u32 wa0 = (u32)sr * 128 + (((u32)scb) ^ ((u32)(sr & 7) << 4));
  const u32 wa1 = (u32)sr * 128 + (((u32)scb + 16) ^ ((u32)(sr & 7) << 4));

  // bias16 staging: per issue i (0..3) wave wq covers rows i*32 + wq*8 + (lane>>3)
  const int r_l = lane >> 3;
  const int gl = (lane & 7) ^ r_l;
  const _Float16* bsrc = bias16 + (size_t)(b * SS + q0 + wq * 8 + r_l) * SS + gl * 8;

  // bias read addresses (fixed): 8B at qq*128 + ((kb*4+rq) ^ (qq&7))*16 + hi*8
  const int qq = wq * 32 + ln;
  int baddr[2][4];
#pragma unroll
  for (int kb = 0; kb < 2; ++kb)
#pragma unroll
    for (int rq = 0; rq < 4; ++rq)
      baddr[kb][rq] = qq * 128 + (((kb * 4 + rq) ^ (ln & 7)) << 4) + hi * 8;

  // ---- prologue: stage tile 0 (bias via gload_lds, K/V via regs) ----
  {
    char* bd = (char*)bbuf[0] + wq * 1024;
#pragma unroll
    for (int i = 0; i < 4; ++i)
      __builtin_amdgcn_global_load_lds((gas1_t)(const void*)(bsrc + (size_t)i * 32 * SS),
                                       (las3_t)(void*)(bd + i * 4096), 16, 0, 0);
  }
  u16x8 kr0, kr1, vr0, vr1;
  kr0 = *(const u16x8*)(kg + 0);
  kr1 = *(const u16x8*)(kg + 8);
  vr0 = *(const u16x8*)(vg + 0);
  vr1 = *(const u16x8*)(vg + 8);
  *(u16x8*)((char*)kbuf[0] + wa0) = kr0;
  *(u16x8*)((char*)kbuf[0] + wa1) = kr1;
  *(u16x8*)((char*)vbuf[0] + wa0) = vr0;
  *(u16x8*)((char*)vbuf[0] + wa1) = vr1;
  __syncthreads();

  f32x16 o0 = {}, o1 = {};
  float m = -1e30f, lsum = 0.f;
  int cur = 0;

  for (int kt = 0; kt < 16; ++kt) {
    // 1. stage next tile: bias[kt+1] -> bbuf[cur^1] (async LDS), K/V[kt+1] -> regs
    if (kt < 15) {
      char* bd = (char*)bbuf[cur ^ 1] + wq * 1024;
      const _Float16* bs = bsrc + (kt + 1) * 64;
#pragma unroll
      for (int i = 0; i < 4; ++i)
        __builtin_amdgcn_global_load_lds((gas1_t)(const void*)(bs + (size_t)i * 32 * SS),
                                         (las3_t)(void*)(bd + i * 4096), 16, 0, 0);
      const size_t k1 = (size_t)(kt + 1) * 64;
      kr0 = *(const u16x8*)(kg + k1 * DD + 0);
      kr1 = *(const u16x8*)(kg + k1 * DD + 8);
      vr0 = *(const u16x8*)(vg + k1 + 0);
      vr1 = *(const u16x8*)(vg + k1 + 8);
    }

    // 2. swapped QK^T: s = mfma(K, Q) -> C: col = q = ln, row(k) = (r&3)+8*(r>>2)+4*hi (+32*kb)
    const char* kb_base = (const char*)kbuf[cur];
    f32x16 s[2];
#pragma unroll
    for (int kb = 0; kb < 2; ++kb) {
      f32x16 acc = {};
#pragma unroll
      for (int d = 0; d < 4; ++d) {
        bf16x8 kf = *(const bf16x8*)(kb_base + (kb * 32 + ln) * 128 + (((u32)(d * 32 + hi * 16)) ^ swz));
        acc = MFMA32(kf, qf[d], acc);
      }
      s[kb] = acc;
    }

    // 3. scale (D^-0.5 = 1/32) + bias (fp16 LDS tile staged LAST tile -> already visible)
    const char* bbr = (const char*)bbuf[cur];
#pragma unroll
    for (int kb = 0; kb < 2; ++kb)
#pragma unroll
      for (int rq = 0; rq < 4; ++rq) {
        f16x4 bv = *(const f16x4*)(bbr + baddr[kb][rq]);
#pragma unroll
        for (int c = 0; c < 4; ++c)
          s[kb][rq * 4 + c] = fmaf(s[kb][rq * 4 + c], 0.03125f, (float)bv[c]);
      }

    // 4. in-register row softmax (row is lane-local; only cross-hi shuffle needed)
    float mt = -1e30f;
#pragma unroll
    for (int r = 0; r < 16; ++r) { mt = fmaxf(mt, s[0][r]); mt = fmaxf(mt, s[1][r]); }
    mt = fmaxf(mt, __shfl_xor(mt, 32));

    bool resc = false;
    float fsc = 1.f;
    if (kt == 0) {
      m = mt;
    } else if (__any(mt > m + 8.f)) {   // T13 defer-max
      float mn = fmaxf(m, mt);
      fsc = __expf(m - mn);
      m = mn;
      resc = true;
    }

    float rs = 0.f;
    u32 wv[2][8];
#pragma unroll
    for (int kb = 0; kb < 2; ++kb)
#pragma unroll
      for (int t = 0; t < 8; ++t) {
        float p0 = __expf(s[kb][2 * t] - m);
        float p1 = __expf(s[kb][2 * t + 1] - m);
        rs += p0 + p1;
        wv[kb][t] = pk2(p0, p1);
      }
    rs += __shfl_xor(rs, 32);
    lsum = lsum * fsc + rs;

    if (resc) {  // rescale O at q' = crow(j,hi), factor fetched via lane broadcast
#pragma unroll
      for (int j = 0; j < 16; ++j) {
        float fv = __shfl(fsc, (j & 3) + 8 * (j >> 2) + 4 * hi);
        o0[j] *= fv; o1[j] *= fv;
      }
    }

    // 5. PV: rebuild P A-fragments in-register (cross-hi shfl), then mfma(P, V)
    const char* vb_base = (const char*)vbuf[cur];
#pragma unroll
    for (int ks = 0; ks < 4; ++ks) {
      const int kb = ks >> 1, i0 = (ks & 1) * 4;
      u32 sA = hi ? wv[kb][i0 + 0] : wv[kb][i0 + 2];
      u32 sB = hi ? wv[kb][i0 + 1] : wv[kb][i0 + 3];
      u32 rA = (u32)__shfl_xor((int)sA, 32);
      u32 rB = (u32)__shfl_xor((int)sB, 32);
      u32 e0 = hi ? rA : wv[kb][i0 + 0];
      u32 e1 = hi ? rB : wv[kb][i0 + 1];
      u32 e2 = hi ? wv[kb][i0 + 2] : rA;
      u32 e3 = hi ? wv[kb][i0 + 3] : rB;
      union { u32x4 u; bf16x8 v; } pc;
      pc.u = (u32x4){e0, e1, e2, e3};
      bf16x8 pa = pc.v;
#pragma unroll
      for (int nv = 0; nv < 2; ++nv) {
        bf16x8 vf = *(const bf16x8*)(vb_base + (nv * 32 + ln) * 128 + (((u32)(ks * 32 + hi * 16)) ^ swz));
        if (nv == 0) o0 = MFMA32(pa, vf, o0);
        else         o1 = MFMA32(pa, vf, o1);
      }
    }

    // 6. write next K/V tile into the other buffer; 7. single end-of-tile barrier
    if (kt < 15) {
      char* kd = (char*)kbuf[cur ^ 1];
      char* vd = (char*)vbuf[cur ^ 1];
      *(u16x8*)(kd + wa0) = kr0;
      *(u16x8*)(kd + wa1) = kr1;
      *(u16x8*)(vd + wa0) = vr0;
      *(u16x8*)(vd + wa1) = vr1;
      __syncthreads();
      cur ^= 1;
    }
  }

  // epilogue: normalize (1/l broadcast via shfl) + write O (bf16)
  float inv = 1.0f / lsum;
#pragma unroll
  for (int j = 0; j < 16; ++j) {
    float iv = __shfl(inv, (j & 3) + 8 * (j >> 2) + 4 * hi);
    int q = q0 + wq * 32 + (j & 3) + 8 * (j >> 2) + 4 * hi;
    u16* op = O + (size_t)(b * SS + q) * DD + h * 64 + ln;
    op[0]  = f2b(o0[j] * iv);
    op[32] = f2b(o1[j] * iv);
  }
}

// ---------------- host launch ----------------
extern "C" void kernel_launch(void* const* d_in, const int* in_sizes, int n_in,
                              void* d_out, int out_size, void* d_ws, size_t ws_size,
                              hipStream_t stream) {
  const float* queries = (const float*)d_in[0];
  const float* keys    = (const float*)d_in[1];
  const float* values  = (const float*)d_in[2];
  const float* bias    = (const float*)d_in[3];
  const float* Wq      = (const float*)d_in[4];
  const float* Wk      = (const float*)d_in[5];
  const float* Wv      = (const float*)d_in[6];
  const float* Wp      = (const float*)d_in[7];
  float* out = (float*)d_out;

  char* ws = (char*)d_ws;
  const size_t MB = 1024 * 1024;
  u16* qb  = (u16*)(ws + 0 * MB);
  u16* kb  = (u16*)(ws + 8 * MB);
  u16* vb  = (u16*)(ws + 16 * MB);
  u16* wqb = (u16*)(ws + 24 * MB);
  u16* wkb = (u16*)(ws + 26 * MB);
  u16* wvb = (u16*)(ws + 28 * MB);
  u16* wpb = (u16*)(ws + 30 * MB);
  u16* Qb  = (u16*)(ws + 32 * MB);
  u16* Kb  = (u16*)(ws + 40 * MB);
  u16* Vtb = (u16*)(ws + 56 * MB);
  // bias16 (8.39 MB) overlays kb — dead after the QKV GEMM
  _Float16* bias16 = (_Float16*)(ws + 8 * MB);
  u16* Ob  = (u16*)(ws + 0 * MB);  // attn output over qb (dead after projections)

  const int nAct = BB * SS * DD;  // 4M
  const int nW = DD * DD;         // 1M

  cvt_all<<<dim3(16384), dim3(256), 0, stream>>>(
      queries, keys, values, Wq, Wk, Wv, Wp,
      qb, kb, vb, wqb, wkb, wvb, wpb);

  // QKV projections: z=0 -> Qb, z=1 -> Kb, z=2 -> Vt (transposed write)
  gemm_bt<u16, true><<<dim3(8, 32, 3), dim3(256), 0, stream>>>(
      qb, wqb, Qb, Vtb, DD, DD, (size_t)nAct, (size_t)nW, (size_t)nAct);

  // bias fp32 -> fp16 (kb region dead from here on)
  cvt_bias<<<dim3(4096), dim3(256), 0, stream>>>(bias, bias16);

  attn_kernel<<<dim3(8, 16, 4), dim3(256), 0, stream>>>(Qb, Kb, Vtb, bias16, Ob);

  gemm_bt<float, false><<<dim3(8, 32, 1), dim3(256), 0, stream>>>(
      Ob, wpb, out, nullptr, DD, DD, 0, 0, 0);
}